// Round 15
// baseline (27.292 us; speedup 1.0000x reference)
//
#include <hip/hip_runtime.h>
#include <hip/hip_bf16.h>
#include <cstdint>

#define DIM 128
#define PSTR 132   // part[] row stride: 128+4 pad -> 2-way (free) bank access

__device__ __forceinline__ float prelu(float x, float a) {
    return x >= 0.f ? x : a * x;
}

// ---------------- weight pre-transform --------------------------------------
// Repack W[128][256][3] (per-thread fragment stride 48B -> 48 lines/wave-load)
// into plane layout W'[c][s][t]: float4 o = (c*3+s)*1024 + t holds the s-th
// float4 of thread t's chunk-c fragment (t = k*8+u), i.e. source float4
// k*192 + c*24 + u*3 + s. Encoder loads become unit-stride (16 lines/instr).
__global__ __launch_bounds__(256) void repack_w(
    const float* __restrict__ Wb2, const float* __restrict__ Wb1,
    const float* __restrict__ Wb0, float* __restrict__ wsout)
{
    const int blk = blockIdx.x;          // 0..287 = 3 matrices x 96 blocks
    const int m = blk / 96;
    const int o = (blk % 96) * 256 + threadIdx.x;   // float4 index 0..24575
    const float* src = m == 0 ? Wb2 : m == 1 ? Wb1 : Wb0;
    const int c = o / 3072;
    const int rem = o - c * 3072;
    const int s = rem >> 10;             // 0..2
    const int t = rem & 1023;
    const int k = t >> 3, u = t & 7;
    const int in_f4 = k * 192 + c * 24 + u * 3 + s;
    const float4 v = *reinterpret_cast<const float4*>(src + in_f4 * 4);
    *reinterpret_cast<float4*>(wsout + ((size_t)m * 98304) + o * 4) = v;
}

// ---- per-thread weight fragment from the repacked planes (coalesced) ----
__device__ __forceinline__ void load_w3(const float* __restrict__ Wt, int c,
                                        int t, float4 w[3]) {
    const float* p = Wt + c * 12288 + t * 4;   // chunk stride 3*1024 float4
    w[0] = *reinterpret_cast<const float4*>(p);
    w[1] = *reinterpret_cast<const float4*>(p + 4096);
    w[2] = *reinterpret_cast<const float4*>(p + 8192);
}

// One 32-d chunk of bilinear accumulation from register weights.
// (Bit-exact verified rounds 10/12/14; weight values identical post-repack.)
template<int J>
__device__ __forceinline__ void bilin_chunk_reg(const float4 w[3], int c,
                                                const float* xbase, int u,
                                                float acc[][3]) {
    const float wf[12] = { w[0].x, w[0].y, w[0].z, w[0].w,
                           w[1].x, w[1].y, w[1].z, w[1].w,
                           w[2].x, w[2].y, w[2].z, w[2].w };
    const int inner = ((c & 3) << 5) + (u << 2);
    const int half = c >> 2;   // which 128-row of the 256-wide concat
#pragma unroll
    for (int j = 0; j < J; ++j) {
        float4 xv = *reinterpret_cast<const float4*>(
            xbase + (2 * j + half) * 128 + inner);
        const float xf[4] = { xv.x, xv.y, xv.z, xv.w };
#pragma unroll
        for (int dl = 0; dl < 4; ++dl)
#pragma unroll
            for (int v = 0; v < 3; ++v)
                acc[j][v] += wf[dl * 3 + v] * xf[dl];
    }
}

// Epilogue: pairwise tree over the 8 u-slices (part stride PSTR).
template<int ROWS>
__device__ __forceinline__ void reduce_part(const float* part, float biasv,
                                            float aval, float* dst, int t) {
    if (t < ROWS * 128) {
        int r = t >> 7, kk = t & 127;
        float p0 = part[(0 * ROWS + r) * PSTR + kk];
        float p1 = part[(1 * ROWS + r) * PSTR + kk];
        float p2 = part[(2 * ROWS + r) * PSTR + kk];
        float p3 = part[(3 * ROWS + r) * PSTR + kk];
        float p4 = part[(4 * ROWS + r) * PSTR + kk];
        float p5 = part[(5 * ROWS + r) * PSTR + kk];
        float p6 = part[(6 * ROWS + r) * PSTR + kk];
        float p7 = part[(7 * ROWS + r) * PSTR + kk];
        float s = ((p0 + p1) + (p2 + p3)) + ((p4 + p5) + (p6 + p7));
        dst[r * 128 + kk] = prelu(s + biasv, aval);
    }
}

// Sampled linear: weights loaded AT USE (two exposed latency hits total).
template<int NODES>
__device__ __forceinline__ void linear_stage(const float* __restrict__ Wsg,
                                             const float* const* x0,
                                             const float* const* x1,
                                             float* part, int k, int u) {
    float4 wv[8];
#pragma unroll
    for (int i = 0; i < 8; ++i)
        wv[i] = *reinterpret_cast<const float4*>(Wsg + k * 256 + ((i * 8 + u) << 2));
#pragma unroll
    for (int n = 0; n < NODES; ++n) {
        float acc = 0.f;
#pragma unroll
        for (int i = 0; i < 8; ++i) {
            const float* xr = (i < 4) ? (x0[n] + (i << 5) + (u << 2))
                                      : (x1[n] + ((i - 4) << 5) + (u << 2));
            float4 xv = *reinterpret_cast<const float4*>(xr);
            acc += wv[i].x * xv.x + wv[i].y * xv.y + wv[i].z * xv.z + wv[i].w * xv.w;
        }
        part[(u * NODES + n) * PSTR + k] = acc;
    }
}

// min 4 waves/EU so the allocator uses the 128-VGPR cap (round-12 lesson).
__global__ __launch_bounds__(1024, 4) void encoder_fused(
    const float* __restrict__ points,
    const float* __restrict__ vec2, const float* __restrict__ vec1,
    const float* __restrict__ vec0,
    const float* __restrict__ Wp,  const float* __restrict__ bp,
    const float* __restrict__ aL,
    const float* __restrict__ wt,  // repacked Wb2'|Wb1'|Wb0' in d_ws
    const float* __restrict__ bb2, const float* __restrict__ a2,
    const float* __restrict__ bb1,
    const float* __restrict__ Ws1, const float* __restrict__ bs1,
    const float* __restrict__ a1,
    const float* __restrict__ bb0,
    const float* __restrict__ Ws0, const float* __restrict__ bs0,
    const float* __restrict__ a0,
    const int* __restrict__ cl2, const int* __restrict__ cr2,
    const int* __restrict__ cl1, const int* __restrict__ cr1,
    const int* __restrict__ cs1,
    const int* __restrict__ cl0, const int* __restrict__ cr0,
    const int* __restrict__ cs0,
    float* __restrict__ out,
    int N3, int N2, int N1)
{
    __shared__ float leaf[12][DIM];
    __shared__ float h2s[5][DIM];
    __shared__ float t1s[2][DIM];
    __shared__ float h1s[2][DIM];
    __shared__ float h0s[DIM];
    __shared__ float part[8 * 5 * PSTR];
    __shared__ int   ljs[12];

    const int b = blockIdx.x;
    const int t = threadIdx.x;
    const int k  = t >> 3;    // output channel 0..127
    const int u  = t & 7;     // d-subchunk 0..7
    const int kk = t & 127;

    const float* Wt2 = wt;
    const float* Wt1 = wt + 98304;
    const float* Wt0 = wt + 196608;

    // ---- uniform index chain ----
    const int m0 = cl0[0], m1 = cr0[0];
    int nj[5];
    nj[0] = cl1[m0]; nj[1] = cr1[m0];
    nj[2] = cl1[m1]; nj[3] = cr1[m1];
    nj[4] = cs0[0];
    if (t == 0) {
        ljs[0] = cl2[nj[0]]; ljs[1] = cr2[nj[0]];
        ljs[2] = cl2[nj[1]]; ljs[3] = cr2[nj[1]];
        ljs[4] = cl2[nj[2]]; ljs[5] = cr2[nj[2]];
        ljs[6] = cl2[nj[3]]; ljs[7] = cr2[nj[3]];
        ljs[8] = cl2[nj[4]]; ljs[9] = cr2[nj[4]];
        ljs[10] = cs1[m0];   ljs[11] = cs1[m1];
    }

    // ---- preloads (scalars, vec triplets) ----
    const float aLv = aL[0], a2v = a2[0], a1v = a1[0], a0v = a0[0];
    const float wp0 = Wp[kk * 3 + 0], wp1 = Wp[kk * 3 + 1], wp2 = Wp[kk * 3 + 2];
    const float bpv = bp[kk];
    const float bb2v = bb2[kk], bb1v = bb1[kk], bs1v = bs1[kk];
    const float bb0v = bb0[kk], bs0v = bs0[kk];
    float v2r[5][3], v1r[2][3], v0r[3];
#pragma unroll
    for (int j = 0; j < 5; ++j) {
        size_t vb = ((size_t)b * N2 + nj[j]) * 3;
        v2r[j][0] = vec2[vb]; v2r[j][1] = vec2[vb + 1]; v2r[j][2] = vec2[vb + 2];
    }
    {
        size_t vb0 = ((size_t)b * N1 + m0) * 3, vb1 = ((size_t)b * N1 + m1) * 3;
        v1r[0][0] = vec1[vb0]; v1r[0][1] = vec1[vb0 + 1]; v1r[0][2] = vec1[vb0 + 2];
        v1r[1][0] = vec1[vb1]; v1r[1][1] = vec1[vb1 + 1]; v1r[1][2] = vec1[vb1 + 2];
    }
    v0r[0] = vec0[b * 3]; v0r[1] = vec0[b * 3 + 1]; v0r[2] = vec0[b * 3 + 2];

    // ---- depth-3 weight pipeline: 4 rotating register slots, all static ----
    float4 w[4][3];
    load_w3(Wt2, 0, t, w[0]);
    load_w3(Wt2, 1, t, w[1]);
    load_w3(Wt2, 2, t, w[2]);

    __syncthreads();                      // ljs visible

    // ---- leaf rows ----
    for (int idx = t; idx < 12 * DIM; idx += 1024) {
        int r = idx >> 7;
        size_t pb = ((size_t)b * N3 + ljs[r]) * 3;
        float p0 = points[pb], p1 = points[pb + 1], p2 = points[pb + 2];
        leaf[r][kk] = prelu(p0 * wp0 + p1 * wp1 + p2 * wp2 + bpv, aLv);
    }
    __syncthreads();                      // leaf visible

    // ================ layer 2: 5 nodes (global chunks 0..7) =================
    float acc2[5][3] = {};
#pragma unroll
    for (int c = 0; c < 8; ++c) {
        if (c < 5) load_w3(Wt2, c + 3, t, w[(c + 3) & 3]);
        else       load_w3(Wt1, c - 5, t, w[(c + 3) & 3]);  // cross-layer
        bilin_chunk_reg<5>(w[c & 3], c, &leaf[0][0], u, acc2);
    }
#pragma unroll
    for (int j = 0; j < 5; ++j) {
        float z = v2r[j][0] * acc2[j][0] + v2r[j][1] * acc2[j][1] +
                  v2r[j][2] * acc2[j][2];
        part[(u * 5 + j) * PSTR + k] = z;
    }
    __syncthreads();
    reduce_part<5>(part, bb2v, a2v, &h2s[0][0], t);
    __syncthreads();

    // ================ layer 1 bilinear: 2 nodes (chunks 8..15) ==============
    float acc1[2][3] = {};
#pragma unroll
    for (int c = 0; c < 8; ++c) {
        if (c < 5) load_w3(Wt1, c + 3, t, w[(c + 3) & 3]);
        else       load_w3(Wt0, c - 5, t, w[(c + 3) & 3]);  // prefetch root
        bilin_chunk_reg<2>(w[c & 3], c, &h2s[0][0], u, acc1);
    }
#pragma unroll
    for (int n = 0; n < 2; ++n) {
        float z = v1r[n][0] * acc1[n][0] + v1r[n][1] * acc1[n][1] +
                  v1r[n][2] * acc1[n][2];
        part[(u * 2 + n) * PSTR + k] = z;
    }
    __syncthreads();
    reduce_part<2>(part, bb1v, a1v, &t1s[0][0], t);
    __syncthreads();

    // ---- layer 1 sampled linear (weights at use) ----
    {
        const float* x0[2] = { &t1s[0][0], &t1s[1][0] };
        const float* x1[2] = { &leaf[10][0], &leaf[11][0] };
        linear_stage<2>(Ws1, x0, x1, part, k, u);
    }
    __syncthreads();
    reduce_part<2>(part, bs1v, a1v, &h1s[0][0], t);
    __syncthreads();

    // ================ root bilinear: 1 node (chunks 16..23) =================
    float acc0[1][3] = {};
#pragma unroll
    for (int c = 0; c < 8; ++c) {
        if (c < 5) load_w3(Wt0, c + 3, t, w[(c + 3) & 3]);
        bilin_chunk_reg<1>(w[c & 3], c, &h1s[0][0], u, acc0);
    }
    {
        float z = v0r[0] * acc0[0][0] + v0r[1] * acc0[0][1] + v0r[2] * acc0[0][2];
        part[u * PSTR + k] = z;
    }
    __syncthreads();
    reduce_part<1>(part, bb0v, a0v, &h0s[0], t);
    __syncthreads();

    // ---- root sampled linear -> output ----
    {
        const float* x0[1] = { &h0s[0] };
        const float* x1[1] = { &h2s[4][0] };
        linear_stage<1>(Ws0, x0, x1, part, k, u);
    }
    __syncthreads();
    if (t < DIM) {
        float p0 = part[0 * PSTR + t], p1 = part[1 * PSTR + t];
        float p2 = part[2 * PSTR + t], p3 = part[3 * PSTR + t];
        float p4 = part[4 * PSTR + t], p5 = part[5 * PSTR + t];
        float p6 = part[6 * PSTR + t], p7 = part[7 * PSTR + t];
        float s = ((p0 + p1) + (p2 + p3)) + ((p4 + p5) + (p6 + p7));
        out[(size_t)b * DIM + t] = prelu(s + bs0v, a0v);
    }
}

// ---------------- launch ---------------------------------------------------
extern "C" void kernel_launch(void* const* d_in, const int* in_sizes, int n_in,
                              void* d_out, int out_size, void* d_ws, size_t ws_size,
                              hipStream_t stream)
{
    const float* points = (const float*)d_in[0];
    const float* vec2   = (const float*)d_in[1];
    const float* vec1   = (const float*)d_in[2];
    const float* vec0   = (const float*)d_in[3];
    const float* Wp     = (const float*)d_in[4];
    const float* bp     = (const float*)d_in[5];
    const float* a_leaf = (const float*)d_in[6];
    const float* Wb2    = (const float*)d_in[7];
    const float* bb2    = (const float*)d_in[8];
    const float* a2     = (const float*)d_in[9];
    const float* Wb1    = (const float*)d_in[10];
    const float* bb1    = (const float*)d_in[11];
    const float* Ws1    = (const float*)d_in[12];
    const float* bs1    = (const float*)d_in[13];
    const float* a1     = (const float*)d_in[14];
    const float* Wb0    = (const float*)d_in[15];
    const float* bb0    = (const float*)d_in[16];
    const float* Ws0    = (const float*)d_in[17];
    const float* bs0    = (const float*)d_in[18];
    const float* a0     = (const float*)d_in[19];
    const int* cl2 = (const int*)d_in[20];
    const int* cr2 = (const int*)d_in[21];
    const int* cl1 = (const int*)d_in[22];
    const int* cr1 = (const int*)d_in[23];
    const int* cs1 = (const int*)d_in[24];
    const int* cl0 = (const int*)d_in[25];
    const int* cr0 = (const int*)d_in[26];
    const int* cs0 = (const int*)d_in[27];

    const int B = 8, N3 = 131072, N2 = 65536, N1 = 1024;
    (void)in_sizes; (void)n_in; (void)out_size; (void)ws_size;

    float* wt = (float*)d_ws;   // 3 x 98304 floats = 1.18 MB repacked weights

    repack_w<<<288, 256, 0, stream>>>(Wb2, Wb1, Wb0, wt);
    encoder_fused<<<B, 1024, 0, stream>>>(
        points, vec2, vec1, vec0,
        Wp, bp, a_leaf,
        wt, bb2, a2,
        bb1, Ws1, bs1, a1,
        bb0, Ws0, bs0, a0,
        cl2, cr2, cl1, cr1, cs1, cl0, cr0, cs0,
        (float*)d_out, N3, N2, N1);
}